// Round 1
// baseline (164.360 us; speedup 1.0000x reference)
//
#include <hip/hip_runtime.h>
#include <stdint.h>

// ---------------- types ----------------
using bf16x8 = __attribute__((ext_vector_type(8))) __bf16;
using f32x4v = __attribute__((ext_vector_type(4))) float;

__device__ __forceinline__ unsigned int f2bf(float f) {
  unsigned int u = __float_as_uint(f);
  return (u + 0x7FFFu + ((u >> 16) & 1u)) >> 16;  // RNE f32->bf16
}

// =====================================================================
// k0: z NCHW f32 [16,256,64,64] -> zt row-major bf16 [65536][256]
// thread: one (n, c-octet). lanes = consecutive n = consecutive hw (coalesced
// reads, 8 strided dword loads); one contiguous 16B store.
// =====================================================================
__global__ __launch_bounds__(256) void k0_zt(const float* __restrict__ z,
                                             ushort* __restrict__ zt) {
  const int T = blockIdx.x * 256 + threadIdx.x;   // 0 .. 2M-1
  const int co = T >> 16;                          // 0..31 c-octet
  const int n  = T & 65535;
  const int b = n >> 12, hw = n & 4095;
  const float* src = z + (((b << 8) + (co << 3)) << 12) + hw;
  unsigned int o[4];
#pragma unroll
  for (int p = 0; p < 4; ++p) {
    const float f0 = src[(size_t)(2 * p) << 12];
    const float f1 = src[(size_t)(2 * p + 1) << 12];
    o[p] = f2bf(f0) | (f2bf(f1) << 16);
  }
  uint4 v; v.x = o[0]; v.y = o[1]; v.z = o[2]; v.w = o[3];
  *(uint4*)(zt + (size_t)n * 256 + co * 8) = v;
}

// =====================================================================
// k0b: codebook f32 [1024][256] -> bf16 + halfnorm = 0.5*||e||^2
// one wave per code.
// =====================================================================
__global__ __launch_bounds__(64) void k0b_cb(const float* __restrict__ cb,
                                             ushort* __restrict__ cbb,
                                             float* __restrict__ hn) {
  const int code = blockIdx.x, l = threadIdx.x;
  const float4 v = *(const float4*)(cb + code * 256 + l * 4);
  float ss = v.x * v.x + v.y * v.y + v.z * v.z + v.w * v.w;
  uint2 p;
  p.x = f2bf(v.x) | (f2bf(v.y) << 16);
  p.y = f2bf(v.z) | (f2bf(v.w) << 16);
  *(uint2*)(cbb + code * 256 + l * 4) = p;
#pragma unroll
  for (int s = 32; s; s >>= 1) ss += __shfl_down(ss, s, 64);
  if (l == 0) hn[code] = 0.5f * ss;
}

// =====================================================================
// k1: argmax over codes of (z.e - 0.5||e||^2) via bf16 MFMA 16x16x32.
// 512 blocks x 256 thr (4 waves, 2x2). Block = 128 rows, loops 8 chunks
// of 128 codes. LDS: A [128][256]bf16 swizzled (64KB) + B same (64KB).
// Staged with global_load_lds(16B), source pre-swizzled (involution
// byte^=((row&7)<<4) within each 512B row) so ds_read_b128 is conflict-free.
// =====================================================================
#define LDS_B_OFF 65536

__global__ __launch_bounds__(256) void k1_argmin(const ushort* __restrict__ zt,
                                                 const ushort* __restrict__ cbb,
                                                 const float* __restrict__ hn,
                                                 int* __restrict__ idxout) {
  extern __shared__ char smem[];
  const int t = threadIdx.x;
  const int w = t >> 6, lane = t & 63;
  const int l15 = lane & 15, g = lane >> 4;
  const int wr = w >> 1, wc = w & 1;
  const int bid = blockIdx.x;

  // ---- stage A once (64KB contiguous, pre-swizzled source) ----
  {
    const char* ga = (const char*)zt + (size_t)bid * 65536;
#pragma unroll
    for (int i = 0; i < 16; ++i) {
      const int L = (i * 256 + t) * 16;
      const int row = L >> 9;
      const int src = (L & ~511) | ((L & 511) ^ ((row & 7) << 4));
      __builtin_amdgcn_global_load_lds(
          (const __attribute__((address_space(1))) unsigned int*)(ga + src),
          (__attribute__((address_space(3))) unsigned int*)(smem + (i * 4096 + w * 1024)),
          16, 0, 0);
    }
  }

  float bestv[4][4];
  int   besti[4][4];
#pragma unroll
  for (int m = 0; m < 4; ++m)
#pragma unroll
    for (int i = 0; i < 4; ++i) { bestv[m][i] = -3.4e38f; besti[m][i] = 0; }

  const int arowbase = wr * 64;
  const int browbase = wc * 64;

  for (int ch = 0; ch < 8; ++ch) {
    if (ch) __syncthreads();          // previous chunk compute done before restage
    {
      const char* gb = (const char*)cbb + (size_t)ch * 65536;
#pragma unroll
      for (int i = 0; i < 16; ++i) {
        const int L = (i * 256 + t) * 16;
        const int row = L >> 9;
        const int src = (L & ~511) | ((L & 511) ^ ((row & 7) << 4));
        __builtin_amdgcn_global_load_lds(
            (const __attribute__((address_space(1))) unsigned int*)(gb + src),
            (__attribute__((address_space(3))) unsigned int*)(smem + (LDS_B_OFF + i * 4096 + w * 1024)),
            16, 0, 0);
      }
    }
    float hnv[4];
#pragma unroll
    for (int n = 0; n < 4; ++n)
      hnv[n] = hn[ch * 128 + browbase + n * 16 + l15];
    __syncthreads();                  // staged data visible

    f32x4v acc[4][4];
#pragma unroll
    for (int m = 0; m < 4; ++m)
#pragma unroll
      for (int n = 0; n < 4; ++n) acc[m][n] = (f32x4v){0.f, 0.f, 0.f, 0.f};

#pragma unroll
    for (int kk = 0; kk < 8; ++kk) {
      const int kbyte = kk * 64 + g * 16;
      bf16x8 a[4], b[4];
#pragma unroll
      for (int m = 0; m < 4; ++m) {
        const int row = arowbase + m * 16 + l15;
        a[m] = *(const bf16x8*)(smem + row * 512 + (kbyte ^ ((row & 7) << 4)));
      }
#pragma unroll
      for (int n = 0; n < 4; ++n) {
        const int row = browbase + n * 16 + l15;
        b[n] = *(const bf16x8*)(smem + LDS_B_OFF + row * 512 + (kbyte ^ ((row & 7) << 4)));
      }
#pragma unroll
      for (int m = 0; m < 4; ++m)
#pragma unroll
        for (int n = 0; n < 4; ++n)
          acc[m][n] = __builtin_amdgcn_mfma_f32_16x16x32_bf16(a[m], b[n], acc[m][n], 0, 0, 0);
    }

#pragma unroll
    for (int m = 0; m < 4; ++m)
#pragma unroll
      for (int n = 0; n < 4; ++n) {
        const int col = ch * 128 + browbase + n * 16 + l15;
#pragma unroll
        for (int i = 0; i < 4; ++i) {
          const float v = acc[m][n][i] - hnv[n];
          if (v > bestv[m][i]) { bestv[m][i] = v; besti[m][i] = col; }
        }
      }
  }

  // intra-wave argmax reduce across the 16 col-lanes (xor 1,2,4,8 stays in group)
#pragma unroll
  for (int m = 0; m < 4; ++m)
#pragma unroll
    for (int i = 0; i < 4; ++i) {
      float v = bestv[m][i]; int ix = besti[m][i];
#pragma unroll
      for (int s = 1; s < 16; s <<= 1) {
        const float ov = __shfl_xor(v, s, 64);
        const int   oi = __shfl_xor(ix, s, 64);
        if (ov > v || (ov == v && oi < ix)) { v = ov; ix = oi; }
      }
      bestv[m][i] = v; besti[m][i] = ix;
    }

  __syncthreads();                    // all waves done reading A/B
  float* lv = (float*)smem;           // [2][128]
  int*   li = (int*)(smem + 1024);    // [2][128]
  if (l15 == 0) {
#pragma unroll
    for (int m = 0; m < 4; ++m)
#pragma unroll
      for (int i = 0; i < 4; ++i) {
        const int row = wr * 64 + m * 16 + g * 4 + i;
        lv[wc * 128 + row] = bestv[m][i];
        li[wc * 128 + row] = besti[m][i];
      }
  }
  __syncthreads();
  if (t < 128) {
    const float v0 = lv[t], v1 = lv[128 + t];
    const int   i0 = li[t], i1 = li[128 + t];
    const bool take1 = (v1 > v0) || (v1 == v0 && i1 < i0);
    idxout[(size_t)bid * 128 + t] = take1 ? i1 : i0;
  }
}

// =====================================================================
// k2: z_q gather (f32 codebook), straight-through output, loss partials.
// thread: one (b, c, hw-quad). Literal f32 arithmetic out = z + (e - z).
// =====================================================================
__global__ __launch_bounds__(256) void k2_out(const float* __restrict__ z,
                                              const float* __restrict__ cb,
                                              const int* __restrict__ idx,
                                              float* __restrict__ out,
                                              float* __restrict__ partial) {
  const int T = blockIdx.x * 256 + threadIdx.x;    // 0..4M-1
  const int q = T & 1023;                          // hw quad
  const int c = (T >> 10) & 255;
  const int b = T >> 18;
  const size_t zoff = (((size_t)b * 256 + c) << 12) + q * 4;
  const float4 zv = *(const float4*)(z + zoff);
  const int4 iv = *(const int4*)(idx + (b << 12) + q * 4);
  const float e0 = cb[iv.x * 256 + c];
  const float e1 = cb[iv.y * 256 + c];
  const float e2 = cb[iv.z * 256 + c];
  const float e3 = cb[iv.w * 256 + c];
  const float d0 = e0 - zv.x, d1 = e1 - zv.y, d2 = e2 - zv.z, d3 = e3 - zv.w;
  float4 ov;
  ov.x = zv.x + d0; ov.y = zv.y + d1; ov.z = zv.z + d2; ov.w = zv.w + d3;
  *(float4*)(out + zoff) = ov;
  float s = d0 * d0 + d1 * d1 + d2 * d2 + d3 * d3;

  __shared__ float red[4];
#pragma unroll
  for (int sh = 32; sh; sh >>= 1) s += __shfl_down(s, sh, 64);
  if ((threadIdx.x & 63) == 0) red[threadIdx.x >> 6] = s;
  __syncthreads();
  if (threadIdx.x == 0)
    partial[blockIdx.x] = red[0] + red[1] + red[2] + red[3];
}

// k3: deterministic fixed-order reduce of 16384 partials -> vq_loss
__global__ __launch_bounds__(256) void k3_loss(const float* __restrict__ partial,
                                               float* __restrict__ loss_out) {
  __shared__ float red[256];
  const int t = threadIdx.x;
  float s = 0.f;
  for (int i = 0; i < 64; ++i) s += partial[t * 64 + i];
  red[t] = s;
  __syncthreads();
  for (int step = 128; step; step >>= 1) {
    if (t < step) red[t] += red[t + step];
    __syncthreads();
  }
  if (t == 0) loss_out[0] = red[0] * (1.25f / 16777216.0f);
}

// =====================================================================
extern "C" void kernel_launch(void* const* d_in, const int* in_sizes, int n_in,
                              void* d_out, int out_size, void* d_ws, size_t ws_size,
                              hipStream_t stream) {
  const float* z  = (const float*)d_in[0];
  const float* cb = (const float*)d_in[1];
  float* out = (float*)d_out;
  char* ob = (char*)d_out;
  // scratch inside d_out (dead before k2 overwrites it):
  ushort* zt  = (ushort*)ob;                 // [65536][256] bf16 : 33554432 B
  ushort* cbb = (ushort*)(ob + 33554432);    // [1024][256] bf16  :   524288 B
  float*  hn  = (float*)(ob + 34078720);     // [1024] f32        :     4096 B
  // ws: needed during k2/k3
  int*   idx     = (int*)d_ws;                       // 262144 B
  float* partial = (float*)((char*)d_ws + 262144);   //  65536 B

  (void)hipFuncSetAttribute((const void*)k1_argmin,
                            hipFuncAttributeMaxDynamicSharedMemorySize, 131072);

  k0_zt<<<dim3(8192), dim3(256), 0, stream>>>(z, zt);
  k0b_cb<<<dim3(1024), dim3(64), 0, stream>>>(cb, cbb, hn);
  k1_argmin<<<dim3(512), dim3(256), 131072, stream>>>(zt, cbb, hn, idx);
  k2_out<<<dim3(16384), dim3(256), 0, stream>>>(z, cb, idx, out, partial);
  k3_loss<<<dim3(1), dim3(256), 0, stream>>>(partial, out + 16777216);
}

// Round 2
// 109.811 us; speedup vs baseline: 1.4968x; 1.4968x over previous
//
#include <hip/hip_runtime.h>
#include <stdint.h>

using bf16x8 = __attribute__((ext_vector_type(8))) __bf16;
using f32x4v = __attribute__((ext_vector_type(4))) float;

__device__ __forceinline__ unsigned int f2bf(float f) {
  unsigned int u = __float_as_uint(f);
  return (u + 0x7FFFu + ((u >> 16) & 1u)) >> 16;  // RNE f32->bf16
}

// =====================================================================
// k0b: codebook f32 [1024][256] -> bf16 (linear) + 0.5*||e||^2
// =====================================================================
__global__ __launch_bounds__(64) void k0b_cb(const float* __restrict__ cb,
                                             ushort* __restrict__ cbb,
                                             float* __restrict__ hn) {
  const int code = blockIdx.x, l = threadIdx.x;
  const float4 v = *(const float4*)(cb + code * 256 + l * 4);
  float ss = v.x * v.x + v.y * v.y + v.z * v.z + v.w * v.w;
  uint2 p;
  p.x = f2bf(v.x) | (f2bf(v.y) << 16);
  p.y = f2bf(v.z) | (f2bf(v.w) << 16);
  *(uint2*)(cbb + code * 256 + l * 4) = p;
#pragma unroll
  for (int s = 32; s; s >>= 1) ss += __shfl_down(ss, s, 64);
  if (l == 0) hn[code] = 0.5f * ss;
}

// =====================================================================
// k1_fused: per block = 128 z-rows (one b, 128 consecutive hw).
//  - A: z NCHW f32 -> bf16 fragment-order LDS (reg path) + Sigma z^2 (f32)
//  - B: 16 chunks x 64 codes, double-buffered global_load_lds (16B),
//       global source pre-permuted to fragment order (linear LDS dest)
//  - argmax of (z.e - 0.5||e||^2), scores kept for loss
//  - epilogue: gather chosen cb rows (coalesced) -> padded LDS -> NCHW out
// LDS map (dyn 138304 B):
//   A frag      [0,      65536)   (mb*8+kk)*1024 + lane*16
//   B frag buf0 [65536,  98304)
//   B frag buf1 [98304, 131072)
//   lv          [131584,132608)  li [132608,133632)  idx [133632,134144)
//   hn_s        [134144,138240)  red [138240,138272)
//   ef (epilogue, overlays A/B): [0, 131584) = float[128][257]
// =====================================================================
__global__ __launch_bounds__(256) void k1_fused(const float* __restrict__ z,
                                                const float* __restrict__ cb,
                                                const ushort* __restrict__ cbb,
                                                const float* __restrict__ hn,
                                                float* __restrict__ out,
                                                float* __restrict__ pz2,
                                                float* __restrict__ ps) {
  extern __shared__ char smem[];
  const int t = threadIdx.x;
  const int w = t >> 6, lane = t & 63;
  const int l15 = lane & 15;
  const int wr = w >> 1, wc = w & 1;
  const int bid = blockIdx.x;
  const int b = bid >> 5;
  const int hw0 = (bid & 31) << 7;
  const float* zb = z + ((size_t)b << 20) + hw0;
  const char* cbbb = (const char*)cbb;

  // ---- B chunk stage: pre-permuted source -> linear fragment-order LDS ----
  auto stageB = [&](int buf, int ch) {
#pragma unroll
    for (int ii = 0; ii < 8; ++ii) {
      const int L = (ii * 256 + t) * 16;     // linear LDS byte offset in chunk
      const int i16 = L >> 4;
      const int slot = i16 & 63;             // lane slot
      const int blk = i16 >> 6;              // = nb*8 + kk
      const int kk = blk & 7, nb = blk >> 3;
      const int c15 = slot & 15, g = slot >> 4;
      const int code = nb * 16 + c15;
      const int so = code * 512 + kk * 64 + g * 16;  // bytes in 64-code chunk
      __builtin_amdgcn_global_load_lds(
          (const __attribute__((address_space(1))) unsigned int*)(cbbb + (size_t)ch * 32768 + so),
          (__attribute__((address_space(3))) unsigned int*)(smem + 65536 + buf * 32768 + L),
          16, 0, 0);
    }
  };
  stageB(0, 0);  // chunk 0 DMA overlaps A staging

  // ---- hn -> LDS ----
  float* hn_s = (float*)(smem + 134144);
  *(float4*)((char*)smem + 134144 + t * 16) = *(const float4*)(hn + 4 * t);

  // ---- A stage: z f32 -> bf16 fragment-order LDS, Sigma z^2 in f32 ----
  float ss = 0.f;
#pragma unroll
  for (int i = 0; i < 4; ++i) {
    const int flat = i * 256 + t;
    const int co = flat >> 5;   // channel octet 0..31
    const int rq = flat & 31;   // row quad
    const int kk = co >> 2, g = co & 3;
    float4 v[8];
#pragma unroll
    for (int j = 0; j < 8; ++j)
      v[j] = *(const float4*)(zb + (size_t)(co * 8 + j) * 4096 + rq * 4);
#pragma unroll
    for (int j = 0; j < 8; ++j) {
      const float* vf = (const float*)&v[j];
      ss += vf[0] * vf[0] + vf[1] * vf[1] + vf[2] * vf[2] + vf[3] * vf[3];
    }
    uint4 q[4];
#pragma unroll
    for (int k = 0; k < 4; ++k) {
      const unsigned int w0 = f2bf(((const float*)&v[0])[k]) | (f2bf(((const float*)&v[1])[k]) << 16);
      const unsigned int w1 = f2bf(((const float*)&v[2])[k]) | (f2bf(((const float*)&v[3])[k]) << 16);
      const unsigned int w2 = f2bf(((const float*)&v[4])[k]) | (f2bf(((const float*)&v[5])[k]) << 16);
      const unsigned int w3 = f2bf(((const float*)&v[6])[k]) | (f2bf(((const float*)&v[7])[k]) << 16);
      q[k] = (uint4){w0, w1, w2, w3};
    }
#pragma unroll
    for (int k = 0; k < 4; ++k) {
      const int kr = (k + rq) & 3;           // rotate to spread write banks
      const int row = rq * 4 + kr;
      const int slot = g * 16 + (row & 15);
      const int mb = row >> 4;
      *(uint4*)(smem + (((mb * 8 + kk) * 64 + slot) << 4)) = q[kr];
    }
  }

  float bestv[4][4];
  int besti[4][4];
#pragma unroll
  for (int m = 0; m < 4; ++m)
#pragma unroll
    for (int i = 0; i < 4; ++i) { bestv[m][i] = -3.4e38f; besti[m][i] = 0; }

  __syncthreads();  // full drain: A writes + hn + chunk0 DMA all visible

  // ---- main loop: 16 chunks x 64 codes, 2-phase pipeline ----
  for (int ch = 0; ch < 16; ++ch) {
    const int cur = ch & 1;
    if (ch < 15) stageB(cur ^ 1, ch + 1);
    const float hnv0 = hn_s[ch * 64 + wc * 32 + l15];
    const float hnv1 = hn_s[ch * 64 + wc * 32 + 16 + l15];
    const int bbase = 65536 + cur * 32768;
    f32x4v acc[4][2];
#pragma unroll
    for (int m = 0; m < 4; ++m)
#pragma unroll
      for (int n = 0; n < 2; ++n) acc[m][n] = (f32x4v){0.f, 0.f, 0.f, 0.f};
#pragma unroll
    for (int kk = 0; kk < 8; ++kk) {
      bf16x8 af[4], bfr[2];
#pragma unroll
      for (int n = 0; n < 2; ++n) {
        const int nb = wc * 2 + n;
        bfr[n] = *(const bf16x8*)(smem + bbase + (((nb * 8 + kk) * 64 + lane) << 4));
      }
#pragma unroll
      for (int m = 0; m < 4; ++m) {
        const int mb = wr * 4 + m;
        af[m] = *(const bf16x8*)(smem + (((mb * 8 + kk) * 64 + lane) << 4));
      }
#pragma unroll
      for (int m = 0; m < 4; ++m)
#pragma unroll
        for (int n = 0; n < 2; ++n)
          acc[m][n] = __builtin_amdgcn_mfma_f32_16x16x32_bf16(af[m], bfr[n], acc[m][n], 0, 0, 0);
    }
#pragma unroll
    for (int m = 0; m < 4; ++m)
#pragma unroll
      for (int n = 0; n < 2; ++n) {
        const int col = ch * 64 + wc * 32 + n * 16 + l15;
        const float hv = n ? hnv1 : hnv0;
#pragma unroll
        for (int i2 = 0; i2 < 4; ++i2) {
          const float vv = acc[m][n][i2] - hv;
          if (vv > bestv[m][i2]) { bestv[m][i2] = vv; besti[m][i2] = col; }
        }
      }
    __builtin_amdgcn_sched_barrier(0);
    asm volatile("s_waitcnt vmcnt(0)" ::: "memory");  // next chunk staged
    __builtin_amdgcn_sched_barrier(0);
    __builtin_amdgcn_s_barrier();
    __builtin_amdgcn_sched_barrier(0);
  }

  // ---- cross-lane argmax within 16-col groups ----
  const int g4 = lane >> 4;
#pragma unroll
  for (int m = 0; m < 4; ++m)
#pragma unroll
    for (int i = 0; i < 4; ++i) {
      float v = bestv[m][i];
      int ix = besti[m][i];
#pragma unroll
      for (int s = 1; s < 16; s <<= 1) {
        const float ov = __shfl_xor(v, s, 64);
        const int oi = __shfl_xor(ix, s, 64);
        if (ov > v || (ov == v && oi < ix)) { v = ov; ix = oi; }
      }
      bestv[m][i] = v; besti[m][i] = ix;
    }

  __syncthreads();
  float* lv = (float*)(smem + 131584);
  int* li = (int*)(smem + 132608);
  int* idx_s = (int*)(smem + 133632);
  if (l15 == 0) {
#pragma unroll
    for (int m = 0; m < 4; ++m)
#pragma unroll
      for (int i = 0; i < 4; ++i) {
        const int row = wr * 64 + m * 16 + g4 * 4 + i;
        lv[wc * 128 + row] = bestv[m][i];
        li[wc * 128 + row] = besti[m][i];
      }
  }
  __syncthreads();
  float sv = 0.f;
  if (t < 128) {
    const float v0 = lv[t], v1 = lv[128 + t];
    const int i0 = li[t], i1 = li[128 + t];
    const bool take1 = (v1 > v0) || (v1 == v0 && i1 < i0);
    sv = take1 ? v1 : v0;
    idx_s[t] = take1 ? i1 : i0;
  }
  // ---- block reductions: pz2 = Sigma z^2, ps = Sigma s* ----
  float zz = ss;
#pragma unroll
  for (int s = 32; s; s >>= 1) {
    zz += __shfl_down(zz, s, 64);
    sv += __shfl_down(sv, s, 64);
  }
  float* red = (float*)(smem + 138240);
  if (lane == 0) { red[w] = zz; red[4 + w] = sv; }
  __syncthreads();
  if (t == 0) {
    pz2[bid] = red[0] + red[1] + red[2] + red[3];
    ps[bid] = red[4] + red[5] + red[6] + red[7];
  }

  // ---- epilogue: chosen rows -> padded LDS [128][257] -> NCHW out ----
  float* ef = (float*)smem;
#pragma unroll 4
  for (int i = 0; i < 32; ++i) {
    const int r = i * 4 + w;
    const int code = idx_s[r];  // wave-uniform broadcast
    const float4 ev = *(const float4*)(cb + (size_t)code * 256 + 4 * lane);
#pragma unroll
    for (int j = 0; j < 4; ++j) {
      const int jj = (j + (lane >> 3)) & 3;  // rotate: conflict-free writes
      ef[r * 257 + 4 * lane + jj] = ((const float*)&ev)[jj];
    }
  }
  __syncthreads();
  float* outb = out + ((size_t)b << 20) + hw0;
#pragma unroll 8
  for (int i = 0; i < 64; ++i) {
    const int c = w * 64 + i;
    outb[(size_t)c * 4096 + lane] = ef[lane * 257 + c];
    outb[(size_t)c * 4096 + 64 + lane] = ef[(lane + 64) * 257 + c];
  }
}

// =====================================================================
// k3: deterministic reduce of 512 block partials -> vq_loss
// =====================================================================
__global__ __launch_bounds__(256) void k3_loss(const float* __restrict__ pz2,
                                               const float* __restrict__ ps,
                                               float* __restrict__ loss_out) {
  __shared__ double red[256];
  const int t = threadIdx.x;
  double s = ((double)pz2[t] - 2.0 * (double)ps[t]) +
             ((double)pz2[t + 256] - 2.0 * (double)ps[t + 256]);
  red[t] = s;
  __syncthreads();
  for (int st = 128; st; st >>= 1) {
    if (t < st) red[t] += red[t + st];
    __syncthreads();
  }
  if (t == 0) loss_out[0] = (float)(red[0] * (1.25 / 16777216.0));
}

// =====================================================================
extern "C" void kernel_launch(void* const* d_in, const int* in_sizes, int n_in,
                              void* d_out, int out_size, void* d_ws, size_t ws_size,
                              hipStream_t stream) {
  (void)in_sizes; (void)n_in; (void)out_size; (void)ws_size;
  const float* z = (const float*)d_in[0];
  const float* cb = (const float*)d_in[1];
  float* out = (float*)d_out;

  char* wsb = (char*)d_ws;
  ushort* cbb = (ushort*)wsb;                    // 524288 B
  float* hn = (float*)(wsb + 524288);            //   4096 B
  float* pz2 = (float*)(wsb + 528384);           //   2048 B
  float* ps = (float*)(wsb + 530432);            //   2048 B

  (void)hipFuncSetAttribute((const void*)k1_fused,
                            hipFuncAttributeMaxDynamicSharedMemorySize, 138304);

  k0b_cb<<<dim3(1024), dim3(64), 0, stream>>>(cb, cbb, hn);
  k1_fused<<<dim3(512), dim3(256), 138304, stream>>>(z, cb, cbb, hn, out, pz2, ps);
  k3_loss<<<dim3(1), dim3(256), 0, stream>>>(pz2, ps, out + 16777216);
}

// Round 4
// 70.327 us; speedup vs baseline: 2.3371x; 1.5614x over previous
//
#include <hip/hip_runtime.h>
#include <stdint.h>

using bf16x8 = __attribute__((ext_vector_type(8))) __bf16;
using f32x4v = __attribute__((ext_vector_type(4))) float;

__device__ __forceinline__ unsigned int f2bf(float f) {
  unsigned int u = __float_as_uint(f);
  return (u + 0x7FFFu + ((u >> 16) & 1u)) >> 16;  // RNE f32->bf16
}

// =====================================================================
// k0b: codebook f32 [1024][256] -> bf16 in MFMA FRAGMENT order + 0.5||e||^2
// fragment unit (nb=code>>4, kk, g, c15): byte addr =
//   (nb*8 + kk)*1024 + (g*16 + (code&15))*16 + j*2,  ch = kk*32 + g*8 + j
// => each 64-code chunk ch is the contiguous 32KB [ch*32768, +32768).
// =====================================================================
__global__ __launch_bounds__(64) void k0b_cb(const float* __restrict__ cb,
                                             char* __restrict__ cbb,
                                             float* __restrict__ hn) {
  const int code = blockIdx.x, l = threadIdx.x;
  const float4 v = *(const float4*)(cb + code * 256 + l * 4);
  float ss = v.x * v.x + v.y * v.y + v.z * v.z + v.w * v.w;
  uint2 p;
  p.x = f2bf(v.x) | (f2bf(v.y) << 16);
  p.y = f2bf(v.z) | (f2bf(v.w) << 16);
  const int addr = (((code >> 4) * 8 + (l >> 3)) << 10) +
                   ((((l & 7) >> 1) * 16 + (code & 15)) << 4) + (l & 1) * 8;
  *(uint2*)(cbb + addr) = p;
#pragma unroll
  for (int s = 32; s; s >>= 1) ss += __shfl_down(ss, s, 64);
  if (l == 0) hn[code] = 0.5f * ss;
}

// =====================================================================
// k1_fused: 512 blocks x 256 thr (4 waves), block = 128 rows (one b,
// 128 consecutive hw). Waves: wr=w>>1 row-band (64 rows), wc=w&1 chan half.
//  - A panel: cooperative LDS-transpose stage -> 32 bf16x8 REGISTERS/wave
//    (each thread: 1 row x 128 channels = 16 octets; kk = wc*4+(grp>>2)
//     spans ALL 8 k-chunks across the wc pair  [R3 bug: grp<8 covered half])
//  - B: 16 chunks x 64 codes, double-buffered linear global_load_lds
//  - per chunk/wave: 16 ds_read_b128 + 64 MFMA (A from regs)
//  - epilogue: gather chosen cb rows -> bf16 LDS [128][258] -> NCHW out
// LDS (72768 B => 2 blocks/CU):
//   B buf0 [0,32768) buf1 [32768,65536)   (A-stage scratch reuses [0,65536))
//   ef overlay [0,66048) bf16[128][258]
//   hn [66048,70144) lv [70144,71168) li [71168,72192)
//   idx [72192,72704) red [72704,72768)
// =====================================================================
#define HN_OFF   66048
#define LV_OFF   70144
#define LI_OFF   71168
#define IDX_OFF  72192
#define RED_OFF  72704
#define LDS_SZ   72768

__global__ __launch_bounds__(256, 2) void k1_fused(const float* __restrict__ z,
                                                   const float* __restrict__ cb,
                                                   const char* __restrict__ cbb,
                                                   const float* __restrict__ hn,
                                                   float* __restrict__ out,
                                                   float* __restrict__ pz2,
                                                   float* __restrict__ ps) {
  extern __shared__ char smem[];
  const int t = threadIdx.x, w = t >> 6, lane = t & 63;
  const int l15 = lane & 15, g4 = lane >> 4;
  const int wr = w >> 1, wc = w & 1;
  const int bid = blockIdx.x;
  const int b = bid >> 5, hw0 = (bid & 31) << 7;

  // ---- A stage: z NCHW f32 -> frag-order LDS scratch (band-cooperative) ----
  // wave (wr,wc): rows = band wr (row = lane), channels wc*128 .. +128.
  const float* zw = z + ((size_t)b << 20) + hw0 + wr * 64 + lane;
  float ss = 0.f;
#pragma unroll 4
  for (int grp = 0; grp < 16; ++grp) {
    float f[8];
#pragma unroll
    for (int j = 0; j < 8; ++j)
      f[j] = zw[(size_t)(wc * 128 + grp * 8 + j) * 4096];
#pragma unroll
    for (int j = 0; j < 8; ++j) ss += f[j] * f[j];
    uint4 q;
    q.x = f2bf(f[0]) | (f2bf(f[1]) << 16);
    q.y = f2bf(f[2]) | (f2bf(f[3]) << 16);
    q.z = f2bf(f[4]) | (f2bf(f[5]) << 16);
    q.w = f2bf(f[6]) | (f2bf(f[7]) << 16);
    const int kk = wc * 4 + (grp >> 2), g = grp & 3;
    const int geff = (g + g4) & 3;  // rotate to spread write banks
    *(uint4*)(smem + wr * 32768 + ((g4 * 8 + kk) << 10) + ((geff * 16 + l15) << 4)) = q;
  }
  // hn -> LDS (1024 floats)
  *(float4*)(smem + HN_OFF + t * 16) = *(const float4*)(hn + 4 * t);
  __syncthreads();

  // ---- A panel -> registers (held for all 16 chunks) ----
  bf16x8 A[4][8];
#pragma unroll
  for (int mb = 0; mb < 4; ++mb)
#pragma unroll
    for (int kk = 0; kk < 8; ++kk) {
      const int geff = (g4 + mb) & 3;
      A[mb][kk] = *(const bf16x8*)(smem + wr * 32768 + ((mb * 8 + kk) << 10) +
                                   ((geff * 16 + l15) << 4));
    }
  __syncthreads();  // scratch reads done before B staging overwrites

  // ---- B chunk stage: linear copy (cbb already fragment-ordered) ----
  auto stageB = [&](int buf, int ch) {
#pragma unroll
    for (int i = 0; i < 8; ++i) {
      __builtin_amdgcn_global_load_lds(
          (const __attribute__((address_space(1))) unsigned int*)
              (cbb + (size_t)ch * 32768 + i * 4096 + w * 1024 + lane * 16),
          (__attribute__((address_space(3))) unsigned int*)
              (smem + buf * 32768 + i * 4096 + w * 1024),
          16, 0, 0);
    }
  };
  stageB(0, 0);

  float bestv[4][4];
  int besti[4][4];
#pragma unroll
  for (int m = 0; m < 4; ++m)
#pragma unroll
    for (int i = 0; i < 4; ++i) { bestv[m][i] = -3.4e38f; besti[m][i] = 0; }

  __syncthreads();  // buf0 staged (syncthreads drains vmcnt)

  // ---- main loop: 16 chunks x 64 codes ----
  for (int ch = 0; ch < 16; ++ch) {
    const int cur = ch & 1;
    if (ch < 15) stageB(cur ^ 1, ch + 1);
    const float hnv0 = *(const float*)(smem + HN_OFF + (ch * 64 + wc * 32 + l15) * 4);
    const float hnv1 = *(const float*)(smem + HN_OFF + (ch * 64 + wc * 32 + 16 + l15) * 4);
    f32x4v acc[4][2];
#pragma unroll
    for (int m = 0; m < 4; ++m)
#pragma unroll
      for (int n = 0; n < 2; ++n) acc[m][n] = (f32x4v){0.f, 0.f, 0.f, 0.f};
#pragma unroll
    for (int kk = 0; kk < 8; ++kk) {
      const bf16x8 b0 = *(const bf16x8*)(smem + cur * 32768 +
                        (((wc * 2 + 0) * 8 + kk) << 10) + (lane << 4));
      const bf16x8 b1 = *(const bf16x8*)(smem + cur * 32768 +
                        (((wc * 2 + 1) * 8 + kk) << 10) + (lane << 4));
#pragma unroll
      for (int m = 0; m < 4; ++m) {
        acc[m][0] = __builtin_amdgcn_mfma_f32_16x16x32_bf16(A[m][kk], b0, acc[m][0], 0, 0, 0);
        acc[m][1] = __builtin_amdgcn_mfma_f32_16x16x32_bf16(A[m][kk], b1, acc[m][1], 0, 0, 0);
      }
    }
#pragma unroll
    for (int m = 0; m < 4; ++m)
#pragma unroll
      for (int n = 0; n < 2; ++n) {
        const int col = ch * 64 + wc * 32 + n * 16 + l15;
        const float hv = n ? hnv1 : hnv0;
#pragma unroll
        for (int i = 0; i < 4; ++i) {
          const float vv = acc[m][n][i] - hv;
          if (vv > bestv[m][i]) { bestv[m][i] = vv; besti[m][i] = col; }
        }
      }
    __syncthreads();  // next chunk staged + all waves done with buf[cur]
  }

  // ---- cross-lane argmax within 16-col groups ----
#pragma unroll
  for (int m = 0; m < 4; ++m)
#pragma unroll
    for (int i = 0; i < 4; ++i) {
      float v = bestv[m][i];
      int ix = besti[m][i];
#pragma unroll
      for (int s = 1; s < 16; s <<= 1) {
        const float ov = __shfl_xor(v, s, 64);
        const int oi = __shfl_xor(ix, s, 64);
        if (ov > v || (ov == v && oi < ix)) { v = ov; ix = oi; }
      }
      bestv[m][i] = v; besti[m][i] = ix;
    }

  float* lv = (float*)(smem + LV_OFF);
  int* li = (int*)(smem + LI_OFF);
  int* idx_s = (int*)(smem + IDX_OFF);
  if (l15 == 0) {
#pragma unroll
    for (int m = 0; m < 4; ++m)
#pragma unroll
      for (int i = 0; i < 4; ++i) {
        const int row = wr * 64 + m * 16 + g4 * 4 + i;
        lv[wc * 128 + row] = bestv[m][i];
        li[wc * 128 + row] = besti[m][i];
      }
  }
  __syncthreads();
  float sv = 0.f;
  if (t < 128) {
    const float v0 = lv[t], v1 = lv[128 + t];
    const int i0 = li[t], i1 = li[128 + t];
    const bool take1 = (v1 > v0) || (v1 == v0 && i1 < i0);
    sv = take1 ? v1 : v0;
    idx_s[t] = take1 ? i1 : i0;
  }
  // block reductions: pz2 = Sigma z^2 (exact cover), ps = Sigma s*
  float zz = ss;
#pragma unroll
  for (int s = 32; s; s >>= 1) {
    zz += __shfl_down(zz, s, 64);
    sv += __shfl_down(sv, s, 64);
  }
  float* red = (float*)(smem + RED_OFF);
  if (lane == 0) { red[w] = zz; red[4 + w] = sv; }
  __syncthreads();  // also: idx_s visible, B bufs dead -> epilogue may overlay
  if (t == 0) {
    pz2[bid] = red[0] + red[1] + red[2] + red[3];
    ps[bid] = red[4] + red[5] + red[6] + red[7];
  }

  // ---- epilogue: chosen rows -> bf16 LDS [128][258] -> NCHW out ----
#pragma unroll 4
  for (int rr = 0; rr < 32; ++rr) {
    const int r = w * 32 + rr;
    const int code = idx_s[r];  // wave-uniform broadcast
    const float4 ev = *(const float4*)(cb + (size_t)code * 256 + lane * 4);
    uint2 p;
    p.x = f2bf(ev.x) | (f2bf(ev.y) << 16);
    p.y = f2bf(ev.z) | (f2bf(ev.w) << 16);
    *(uint2*)(smem + r * 516 + lane * 8) = p;
  }
  __syncthreads();
  float* outb = out + ((size_t)b << 20) + hw0;
#pragma unroll 4
  for (int cc = 0; cc < 64; ++cc) {
    const int c = w * 64 + cc;
#pragma unroll
    for (int h = 0; h < 2; ++h) {
      const int row = h * 64 + lane;
      const ushort u = *(const ushort*)(smem + row * 516 + c * 2);
      outb[(size_t)c * 4096 + row] = __uint_as_float(((unsigned)u) << 16);
    }
  }
}

// =====================================================================
// k3: deterministic reduce of 512 block partials -> vq_loss
// =====================================================================
__global__ __launch_bounds__(256) void k3_loss(const float* __restrict__ pz2,
                                               const float* __restrict__ ps,
                                               float* __restrict__ loss_out) {
  __shared__ double red[256];
  const int t = threadIdx.x;
  double s = ((double)pz2[t] - 2.0 * (double)ps[t]) +
             ((double)pz2[t + 256] - 2.0 * (double)ps[t + 256]);
  red[t] = s;
  __syncthreads();
  for (int st = 128; st; st >>= 1) {
    if (t < st) red[t] += red[t + st];
    __syncthreads();
  }
  if (t == 0) loss_out[0] = (float)(red[0] * (1.25 / 16777216.0));
}

// =====================================================================
extern "C" void kernel_launch(void* const* d_in, const int* in_sizes, int n_in,
                              void* d_out, int out_size, void* d_ws, size_t ws_size,
                              hipStream_t stream) {
  (void)in_sizes; (void)n_in; (void)out_size; (void)ws_size;
  const float* z = (const float*)d_in[0];
  const float* cb = (const float*)d_in[1];
  float* out = (float*)d_out;

  char* wsb = (char*)d_ws;
  char* cbb = wsb;                               // 524288 B (fragment-ordered bf16)
  float* hn = (float*)(wsb + 524288);            //   4096 B
  float* pz2 = (float*)(wsb + 528384);           //   2048 B
  float* ps = (float*)(wsb + 530432);            //   2048 B

  (void)hipFuncSetAttribute((const void*)k1_fused,
                            hipFuncAttributeMaxDynamicSharedMemorySize, LDS_SZ);

  k0b_cb<<<dim3(1024), dim3(64), 0, stream>>>(cb, cbb, hn);
  k1_fused<<<dim3(512), dim3(256), LDS_SZ, stream>>>(z, cb, cbb, hn, out, pz2, ps);
  k3_loss<<<dim3(1), dim3(256), 0, stream>>>(pz2, ps, out + 16777216);
}